// Round 6
// baseline (26390.192 us; speedup 1.0000x reference)
//
#include <hip/hip_runtime.h>

// ---------------------------------------------------------------------------
// MultilayerGRU  B=64 S=1024 I=128 H=512 L=3 O=128
// Round 6 = round 5 with the inline-asm store (128-bit "v" input operand,
// unsupported by LLVM) replaced by 2x 64-bit relaxed agent-scope atomic
// stores (proven bypass primitive from rounds 3-4).
//   - 48 WGs = 3 layers x 16 col-slices (32 cols each), 8 waves (4 rz + 4 g)
//   - 16B asm bypass loads (sc0 sc1); publishes via LDS-staged coalesced
//     2x8B write-through atomic stores
//   - Wh in LDS, K-major layout [gate][K-octet][col][8] -> 2-way banks (free)
//   - Wx streamed as normal cached loads (static weights, pre-cvt to bf16)
// ---------------------------------------------------------------------------

typedef float f32x4 __attribute__((ext_vector_type(4)));
typedef __bf16 bf16x8 __attribute__((ext_vector_type(8)));

__device__ __forceinline__ unsigned short f2bf(float x) {
  unsigned int u = __builtin_bit_cast(unsigned int, x);
  u += 0x7fffu + ((u >> 16) & 1u);   // round-to-nearest-even
  return (unsigned short)(u >> 16);
}
__device__ __forceinline__ f32x4 mfma16(int4 a, int4 b, f32x4 c) {
  return __builtin_amdgcn_mfma_f32_16x16x32_bf16(
      __builtin_bit_cast(bf16x8, a), __builtin_bit_cast(bf16x8, b), c, 0, 0, 0);
}
__device__ __forceinline__ float sig_(float x) { return 1.0f / (1.0f + __expf(-x)); }
__device__ __forceinline__ float tanh_(float x) {
  float ax = fabsf(x);
  float e  = __expf(2.0f * ax);
  float t  = 1.0f - 2.0f / (e + 1.0f);
  return x < 0.0f ? -t : t;
}

// ---- coherence-point (cross-XCD) access helpers ----
__device__ __forceinline__ void issue_ld16(const unsigned short* p, int4& d) {
  asm volatile("global_load_dwordx4 %0, %1, off sc0 sc1"
               : "=v"(d) : "v"(p) : "memory");
}
__device__ __forceinline__ void st_wt128(unsigned short* p, int4 v) {
  unsigned long long lo = ((unsigned long long)(unsigned int)v.y << 32) | (unsigned int)v.x;
  unsigned long long hi = ((unsigned long long)(unsigned int)v.w << 32) | (unsigned int)v.z;
  __hip_atomic_store((unsigned long long*)p,     lo, __ATOMIC_RELAXED, __HIP_MEMORY_SCOPE_AGENT);
  __hip_atomic_store((unsigned long long*)p + 1, hi, __ATOMIC_RELAXED, __HIP_MEMORY_SCOPE_AGENT);
}
__device__ __forceinline__ void wait_vm0() {
  asm volatile("s_waitcnt vmcnt(0)" ::: "memory");
}
__device__ __forceinline__ void st_wt16(unsigned short* p, unsigned short v) {
  __hip_atomic_store(p, v, __ATOMIC_RELAXED, __HIP_MEMORY_SCOPE_AGENT);
}
__device__ __forceinline__ void st_flag(int* p, int v) {
  __hip_atomic_store(p, v, __ATOMIC_RELAXED, __HIP_MEMORY_SCOPE_AGENT);
}
__device__ __forceinline__ void poll16(const int* f, int need) {
  int lane = threadIdx.x & 63;
  int v = need;
  if (lane < 16) v = __hip_atomic_load((int*)(f + lane), __ATOMIC_RELAXED, __HIP_MEMORY_SCOPE_AGENT);
  while (__any(v < need)) {
    __builtin_amdgcn_s_sleep(1);
    if (lane < 16) v = __hip_atomic_load((int*)(f + lane), __ATOMIC_RELAXED, __HIP_MEMORY_SCOPE_AGENT);
  }
}

// ---------------------------------------------------------------------------
__global__ void cvt_bf16(const float* __restrict__ src, unsigned short* __restrict__ dst, int n4) {
  int i = blockIdx.x * blockDim.x + threadIdx.x;
  if (i < n4) {
    float4 v = *(const float4*)(src + (size_t)i * 4);
    ushort4 o;
    o.x = f2bf(v.x); o.y = f2bf(v.y); o.z = f2bf(v.z); o.w = f2bf(v.w);
    *(ushort4*)(dst + (size_t)i * 4) = o;
  }
}

// X (64,1024,128) f32 -> Xt row (t*64+b), 128 bf16
__global__ void xt_k(const float* __restrict__ X, unsigned short* __restrict__ Xt) {
  int idx = blockIdx.x * 256 + threadIdx.x;
  int i4 = idx & 31, rest = idx >> 5;
  int t = rest & 1023, b = rest >> 10;
  float4 v = *(const float4*)(X + (size_t)(b * 1024 + t) * 128 + i4 * 4);
  ushort4 o;
  o.x = f2bf(v.x); o.y = f2bf(v.y); o.z = f2bf(v.z); o.w = f2bf(v.w);
  *(ushort4*)(Xt + (size_t)(t * 64 + b) * 128 + i4 * 4) = o;
}

// ---------------------------------------------------------------------------
// C[M,N] = A[M,K] @ W[N,K]^T  (bf16). mode 0: bf16 out; mode 2: fp32+bias,
// row remap m=(t*64+b) -> out row b*1024+t (final Y).
// ---------------------------------------------------------------------------
__global__ __launch_bounds__(256)
void gemm_bt(const unsigned short* __restrict__ A, const unsigned short* __restrict__ W,
             void* __restrict__ Cout, const float* __restrict__ bias,
             int M, int N, int K, int mode) {
  __shared__ unsigned short As[128][72];
  __shared__ unsigned short Bs[128][72];
  const int tid  = threadIdx.x;
  const int lane = tid & 63;
  const int wave = tid >> 6;
  const int wr = wave >> 1, wc = wave & 1;
  const int m0 = blockIdx.x * 128, n0 = blockIdx.y * 128;

  f32x4 acc[4][4];
  for (int i = 0; i < 4; i++)
    for (int j = 0; j < 4; j++) acc[i][j] = f32x4{0.f, 0.f, 0.f, 0.f};

  for (int k0 = 0; k0 < K; k0 += 64) {
    int4 va[4], vb[4];
#pragma unroll
    for (int it = 0; it < 4; it++) {
      int q = tid + it * 256;
      int r = q >> 3, kc = q & 7;
      va[it] = *(const int4*)(A + (size_t)(m0 + r) * K + k0 + kc * 8);
      vb[it] = *(const int4*)(W + (size_t)(n0 + r) * K + k0 + kc * 8);
    }
    __syncthreads();
#pragma unroll
    for (int it = 0; it < 4; it++) {
      int q = tid + it * 256;
      int r = q >> 3, kc = q & 7;
      *(int4*)&As[r][kc * 8] = va[it];
      *(int4*)&Bs[r][kc * 8] = vb[it];
    }
    __syncthreads();
#pragma unroll
    for (int kc = 0; kc < 2; kc++) {
      int koff = kc * 32 + (lane >> 4) * 8;
      int4 af[4], bfr[4];
#pragma unroll
      for (int mt = 0; mt < 4; mt++) af[mt]  = *(const int4*)&As[wr * 64 + mt * 16 + (lane & 15)][koff];
#pragma unroll
      for (int nt = 0; nt < 4; nt++) bfr[nt] = *(const int4*)&Bs[wc * 64 + nt * 16 + (lane & 15)][koff];
#pragma unroll
      for (int mt = 0; mt < 4; mt++)
#pragma unroll
        for (int nt = 0; nt < 4; nt++)
          acc[mt][nt] = mfma16(af[mt], bfr[nt], acc[mt][nt]);
    }
  }

#pragma unroll
  for (int mt = 0; mt < 4; mt++)
#pragma unroll
    for (int nt = 0; nt < 4; nt++)
#pragma unroll
      for (int rg = 0; rg < 4; rg++) {
        int m = m0 + wr * 64 + mt * 16 + (lane >> 4) * 4 + rg;
        int n = n0 + wc * 64 + nt * 16 + (lane & 15);
        float v = acc[mt][nt][rg];
        if (mode == 0) {
          ((unsigned short*)Cout)[(size_t)m * N + n] = f2bf(v);
        } else {
          ((float*)Cout)[(size_t)((m & 63) * 1024 + (m >> 6)) * N + n] = v + bias[n];
        }
      }
}

// ---------------------------------------------------------------------------
// Fused 3-layer pipelined recurrence. 48 WGs = 3 layers x 16 slices (32 cols).
// 8 waves: waves 0-3 = rz (mtile = wave), waves 4-7 = g (mtile = wave-4).
// Ring depth 128 slots; flags: hfl[3][16], ufl[3][16], cpr[3][16].
// ---------------------------------------------------------------------------
__global__ __launch_bounds__(512, 2)
void gru_fused(const unsigned short* __restrict__ Whzb, const unsigned short* __restrict__ Whrb,
               const unsigned short* __restrict__ Whgb,
               const unsigned short* __restrict__ Wxzb, const unsigned short* __restrict__ Wxrb,
               const unsigned short* __restrict__ Wxgb,
               const unsigned short* __restrict__ Wx0zb, const unsigned short* __restrict__ Wx0rb,
               const unsigned short* __restrict__ Wx0gb,
               const float* __restrict__ bz, const float* __restrict__ br,
               const float* __restrict__ bg,
               const unsigned short* __restrict__ Xt,   // (S*B,128) bf16
               const float* __restrict__ h0,            // (B,L,H) fp32
               unsigned short* __restrict__ ring,       // 3 x 128 x (64*512) bf16
               unsigned short* __restrict__ ubc,        // 3 x (64*512) bf16
               int* __restrict__ flags,
               unsigned short* __restrict__ Hbuf,       // (S*B,512) bf16 (layer2)
               float* __restrict__ hidout) {            // (B,L,H) fp32
  const int bid  = blockIdx.x;
  const int L    = bid >> 4;         // layer 0..2
  const int mem  = bid & 15;         // col slice 0..15
  const int cbase = mem * 32;
  const int tid  = threadIdx.x;
  const int lane = tid & 63;
  const int wave = tid >> 6;         // 0..7
  const int isg  = wave >> 2;        // 0 = rz, 1 = g
  const int mtile = wave & 3;

  // K-major weight LDS: [gate 0=z,1=r,2=g][K-octet 0..63][col 0..31][8 bf16]
  __shared__ unsigned short Whs[3][64][32][8];   // 98,304 B
  __shared__ float hloc[64][33];                 // own-slice h, fp32
  __shared__ float zbuf[64][33];
  __shared__ unsigned short un[64][40];          // u bf16 staging
  __shared__ unsigned short hnew[64][40];

  // ---- stage Wh (bf16 global -> K-major LDS) ----
  {
    const unsigned short* whb[3] = { Whzb + (size_t)L * 262144,
                                     Whrb + (size_t)L * 262144,
                                     Whgb + (size_t)L * 262144 };
    for (int idx = tid; idx < 6144; idx += 512) {
      int g = idx >> 11, r = idx & 2047;
      int o = r >> 5, c = r & 31;
      *(int4*)&Whs[g][o][c][0] = *(const int4*)(whb[g] + (size_t)(cbase + c) * 512 + o * 8);
    }
  }
  unsigned short* myring = ring + (size_t)L * 4194304;                 // 128*32768 shorts
  const unsigned short* upring = ring + (size_t)(L > 0 ? L - 1 : 0) * 4194304;
  unsigned short* ubc_l = ubc + (size_t)L * 32768;

  // ---- init h(-1): hloc + ring slot 0 ----
  for (int q = tid; q < 2048; q += 512) {
    int row = q >> 5, c = q & 31;
    float v = h0[(size_t)row * 1536 + L * 512 + cbase + c];
    hloc[row][c] = v;
    st_wt16(&myring[row * 512 + cbase + c], f2bf(v));
  }
  wait_vm0();
  __syncthreads();

  int* hfl = flags;
  int* ufl = flags + 48;
  int* cpr = flags + 96;
  if (tid == 0) st_flag(&hfl[L * 16 + mem], 1);

  const int l15 = lane & 15;
  const int kq  = lane >> 4;
  const int m16 = mtile * 16;
  const int arow = m16 + l15;

  // bias registers (per lane, 2 col-tiles)
  float bz2[2], br2[2], bg2[2];
#pragma unroll
  for (int T = 0; T < 2; T++) {
    bz2[T] = bz[(size_t)L * 512 + cbase + T * 16 + l15];
    br2[T] = br[(size_t)L * 512 + cbase + T * 16 + l15];
    bg2[T] = bg[(size_t)L * 512 + cbase + T * 16 + l15];
  }

  // x-weight base pointers (cached streams)
  const unsigned short *BxzT[2], *BxrT[2], *BxgT[2];
#pragma unroll
  for (int T = 0; T < 2; T++) {
    if (L > 0) {
      size_t off = (size_t)(L - 1) * 262144 + (size_t)(cbase + T * 16 + l15) * 512 + kq * 8;
      BxzT[T] = Wxzb + off; BxrT[T] = Wxrb + off; BxgT[T] = Wxgb + off;
    } else {
      size_t off = (size_t)(cbase + T * 16 + l15) * 128 + kq * 8;
      BxzT[T] = Wx0zb + off; BxrT[T] = Wx0rb + off; BxgT[T] = Wx0gb + off;
    }
  }

  f32x4 gx[2];

  for (int t = 0; t < 1024; t++) {
    const int slot_r = t & 127;
    const int slot_w = (t + 1) & 127;

    if (isg == 0) {
      // ---------------- phase 1 (rz): r and z gates ----------------
      if (L > 0) poll16(hfl + (L - 1) * 16, t + 2);
      poll16(hfl + L * 16, t + 1);
      int4 hf[16], xf[16];
      const unsigned short* hr = myring + (size_t)slot_r * 32768 + arow * 512 + kq * 8;
#pragma unroll
      for (int kc = 0; kc < 16; kc++) issue_ld16(hr + kc * 32, hf[kc]);
      if (L > 0) {
        const unsigned short* xr = upring + (size_t)slot_w * 32768 + arow * 512 + kq * 8;
#pragma unroll
        for (int kc = 0; kc < 16; kc++) issue_ld16(xr + kc * 32, xf[kc]);
      } else {
        const unsigned short* xr = Xt + (size_t)(t * 64 + arow) * 128 + kq * 8;
#pragma unroll
        for (int kc = 0; kc < 4; kc++) xf[kc] = *(const int4*)(xr + kc * 32);
      }
      f32x4 az[2], ar[2];
#pragma unroll
      for (int T = 0; T < 2; T++) { az[T] = f32x4{0.f,0.f,0.f,0.f}; ar[T] = f32x4{0.f,0.f,0.f,0.f}; }
      wait_vm0();
      // x-pass (B from cache)
      if (L > 0) {
#pragma unroll
        for (int kc = 0; kc < 16; kc++)
#pragma unroll
          for (int T = 0; T < 2; T++) {
            az[T] = mfma16(xf[kc], *(const int4*)(BxzT[T] + kc * 32), az[T]);
            ar[T] = mfma16(xf[kc], *(const int4*)(BxrT[T] + kc * 32), ar[T]);
          }
      } else {
#pragma unroll
        for (int kc = 0; kc < 4; kc++)
#pragma unroll
          for (int T = 0; T < 2; T++) {
            az[T] = mfma16(xf[kc], *(const int4*)(BxzT[T] + kc * 32), az[T]);
            ar[T] = mfma16(xf[kc], *(const int4*)(BxrT[T] + kc * 32), ar[T]);
          }
      }
      // h-pass (B from LDS, K-major)
#pragma unroll
      for (int kc = 0; kc < 16; kc++)
#pragma unroll
        for (int T = 0; T < 2; T++) {
          az[T] = mfma16(hf[kc], *(const int4*)&Whs[0][kc * 4 + kq][T * 16 + l15][0], az[T]);
          ar[T] = mfma16(hf[kc], *(const int4*)&Whs[1][kc * 4 + kq][T * 16 + l15][0], ar[T]);
        }
      // elementwise: z -> zbuf, u = r*h -> un
#pragma unroll
      for (int T = 0; T < 2; T++)
#pragma unroll
        for (int rg = 0; rg < 4; rg++) {
          int row = m16 + kq * 4 + rg;
          int c = T * 16 + l15;
          zbuf[row][c] = sig_(az[T][rg] + bz2[T]);
          float rv = sig_(ar[T][rg] + br2[T]);
          un[row][c] = f2bf(rv * hloc[row][c]);
        }
    } else {
      // ---------------- phase 1 (g): gx = Wxg . x ----------------
      gx[0] = f32x4{0.f,0.f,0.f,0.f}; gx[1] = f32x4{0.f,0.f,0.f,0.f};
      if (L > 0) {
        poll16(hfl + (L - 1) * 16, t + 2);
        int4 xf[16];
        const unsigned short* xr = upring + (size_t)slot_w * 32768 + arow * 512 + kq * 8;
#pragma unroll
        for (int kc = 0; kc < 16; kc++) issue_ld16(xr + kc * 32, xf[kc]);
        wait_vm0();
#pragma unroll
        for (int kc = 0; kc < 16; kc++)
#pragma unroll
          for (int T = 0; T < 2; T++)
            gx[T] = mfma16(xf[kc], *(const int4*)(BxgT[T] + kc * 32), gx[T]);
      } else {
        const unsigned short* xr = Xt + (size_t)(t * 64 + arow) * 128 + kq * 8;
#pragma unroll
        for (int kc = 0; kc < 4; kc++) {
          int4 x1 = *(const int4*)(xr + kc * 32);
#pragma unroll
          for (int T = 0; T < 2; T++)
            gx[T] = mfma16(x1, *(const int4*)(BxgT[T] + kc * 32), gx[T]);
        }
      }
    }
    __syncthreads();                       // A: un/zbuf ready
    // coop u publish (4 KB, write-through 2x8B)
    if (tid < 256) {
      int4 v = *(const int4*)&un[tid >> 2][(tid & 3) * 8];
      st_wt128(ubc_l + (tid >> 2) * 512 + cbase + (tid & 3) * 8, v);
    }
    wait_vm0();
    __syncthreads();                       // A2: all stores acked
    if (tid == 0) st_flag(&ufl[L * 16 + mem], t + 1);

    if (isg == 1) {
      // ---------------- phase 2 (g): u-pass + h update ----------------
      poll16(ufl + L * 16, t + 1);
      int4 uf[16];
      const unsigned short* ur = ubc_l + arow * 512 + kq * 8;
#pragma unroll
      for (int kc = 0; kc < 16; kc++) issue_ld16(ur + kc * 32, uf[kc]);
      f32x4 ag[2] = { gx[0], gx[1] };
      wait_vm0();
#pragma unroll
      for (int kc = 0; kc < 16; kc++)
#pragma unroll
        for (int T = 0; T < 2; T++)
          ag[T] = mfma16(uf[kc], *(const int4*)&Whs[2][kc * 4 + kq][T * 16 + l15][0], ag[T]);
#pragma unroll
      for (int T = 0; T < 2; T++)
#pragma unroll
        for (int rg = 0; rg < 4; rg++) {
          int row = m16 + kq * 4 + rg;
          int c = T * 16 + l15;
          float gv = tanh_(ag[T][rg] + bg2[T]);
          float z  = zbuf[row][c];
          float h  = hloc[row][c];
          float hn = z * h + (1.0f - z) * gv;
          hloc[row][c] = hn;
          hnew[row][c] = f2bf(hn);
          if (t == 1023)
            hidout[(size_t)row * 1536 + L * 512 + cbase + c] = hn;
        }
    }
    // ring back-pressure (depth 128, slack 96, checked every 32 steps)
    if (L < 2 && t >= 96 && (t & 31) == 0) poll16(cpr + (L + 1) * 16, t - 96);
    __syncthreads();                       // B: hnew ready
    // coop h publish (ring, + Hbuf for layer 2)
    if (tid < 256) {
      int4 v = *(const int4*)&hnew[tid >> 2][(tid & 3) * 8];
      st_wt128(myring + (size_t)slot_w * 32768 + (tid >> 2) * 512 + cbase + (tid & 3) * 8, v);
      if (L == 2)
        *(int4*)&Hbuf[(size_t)t * 32768 + (tid >> 2) * 512 + cbase + (tid & 3) * 8] = v;
    }
    wait_vm0();
    __syncthreads();                       // B2
    if (tid == 0) {
      st_flag(&hfl[L * 16 + mem], t + 2);
      if (L > 0 && (t & 31) == 31) st_flag(&cpr[L * 16 + mem], t);
    }
  }
}

// ---------------------------------------------------------------------------
// launcher
// ---------------------------------------------------------------------------
extern "C" void kernel_launch(void* const* d_in, const int* in_sizes, int n_in,
                              void* d_out, int out_size, void* d_ws, size_t ws_size,
                              hipStream_t stream) {
  const float* X    = (const float*)d_in[0];
  const float* H0   = (const float*)d_in[1];
  const float* Wx0z = (const float*)d_in[2];
  const float* Wx0r = (const float*)d_in[3];
  const float* Wx0g = (const float*)d_in[4];
  const float* Wxz  = (const float*)d_in[5];
  const float* Wxr  = (const float*)d_in[6];
  const float* Wxg  = (const float*)d_in[7];
  const float* Whz  = (const float*)d_in[8];
  const float* Whr  = (const float*)d_in[9];
  const float* Whg  = (const float*)d_in[10];
  const float* bz   = (const float*)d_in[11];
  const float* br   = (const float*)d_in[12];
  const float* bg   = (const float*)d_in[13];
  const float* Wy   = (const float*)d_in[14];
  const float* by   = (const float*)d_in[15];

  char* w = (char*)d_ws;
  unsigned short* Xt    = (unsigned short*)(w + 0);          // 16,777,216
  unsigned short* Wyb   = (unsigned short*)(w + 16777216);   // 131,072
  unsigned short* Whzb  = (unsigned short*)(w + 16908288);   // 1,572,864
  unsigned short* Whrb  = (unsigned short*)(w + 18481152);
  unsigned short* Whgb  = (unsigned short*)(w + 20054016);
  unsigned short* Wxzb  = (unsigned short*)(w + 21626880);   // 1,048,576
  unsigned short* Wxrb  = (unsigned short*)(w + 22675456);
  unsigned short* Wxgb  = (unsigned short*)(w + 23724032);
  unsigned short* Wx0zb = (unsigned short*)(w + 24772608);   // 131,072
  unsigned short* Wx0rb = (unsigned short*)(w + 24903680);
  unsigned short* Wx0gb = (unsigned short*)(w + 25034752);
  unsigned short* ring  = (unsigned short*)(w + 25165824);   // 25,165,824
  unsigned short* ubc   = (unsigned short*)(w + 50331648);   // 196,608
  unsigned short* Hb    = (unsigned short*)(w + 50528256);   // 67,108,864
  int* flags            = (int*)(w + 117637120);             // 2048
  // total ~112.2 MB

  (void)hipMemsetAsync(flags, 0, 2048, stream);

  auto cvt = [&](const float* s, unsigned short* d, int n) {
    int n4 = n / 4;
    cvt_bf16<<<dim3((n4 + 255) / 256), dim3(256), 0, stream>>>(s, d, n4);
  };
  xt_k<<<dim3(8192), dim3(256), 0, stream>>>(X, Xt);
  cvt(Wy, Wyb, 65536);
  cvt(Whz, Whzb, 786432);
  cvt(Whr, Whrb, 786432);
  cvt(Whg, Whgb, 786432);
  cvt(Wxz, Wxzb, 524288);
  cvt(Wxr, Wxrb, 524288);
  cvt(Wxg, Wxgb, 524288);
  cvt(Wx0z, Wx0zb, 65536);
  cvt(Wx0r, Wx0rb, 65536);
  cvt(Wx0g, Wx0gb, 65536);

  float* hidout = (float*)d_out + 8388608;

  gru_fused<<<dim3(48), dim3(512), 0, stream>>>(
      Whzb, Whrb, Whgb, Wxzb, Wxrb, Wxgb, Wx0zb, Wx0rb, Wx0gb,
      bz, br, bg, Xt, H0, ring, ubc, flags, Hb, hidout);

  // Y = H2 @ Wy^T + by  -> (B,S,O) fp32
  gemm_bt<<<dim3(512, 1), 256, 0, stream>>>(Hb, Wyb, d_out, by, 65536, 128, 512, 2);
}

// Round 7
// 22267.827 us; speedup vs baseline: 1.1851x; 1.1851x over previous
//
#include <hip/hip_runtime.h>

// ---------------------------------------------------------------------------
// MultilayerGRU  B=64 S=1024 I=128 H=512 L=3 O=128
// Round 7: back to the PROVEN per-layer chunked topology (round 3, 7.1us/step
// stable) with a leaner step:
//   - 64 WGs = 4 batch-groups x 16 col-slices (CC=32), 2 waves/WG
//   - wave0: h loaded ONCE (16x16B bypass asm loads), r-MFMA, LDS-staged
//     coalesced 16B u-publish, z-MFMA overlapping the store-ack, flag
//   - wave1: poll u (no barrier in front), load u, g-MFMA, blend, coalesced
//     h publish (+Hbuf), flag
//   - Wh fp32->bf16 staged in-kernel to K-major LDS (2-way banks = free)
//   - workspace layout byte-compatible with round-3's proven 138.2 MB
// Fused 3-layer variants (r4/r6) both plateaued at 25.5us/step with huge
// run variance -> fusion abandoned on evidence.
// ---------------------------------------------------------------------------

typedef float f32x4 __attribute__((ext_vector_type(4)));
typedef __bf16 bf16x8 __attribute__((ext_vector_type(8)));

#define CT 256   // timesteps per chunk
#define CC 32    // H-columns per workgroup slice

__device__ __forceinline__ unsigned short f2bf(float x) {
  unsigned int u = __builtin_bit_cast(unsigned int, x);
  u += 0x7fffu + ((u >> 16) & 1u);   // round-to-nearest-even
  return (unsigned short)(u >> 16);
}
__device__ __forceinline__ float bf2f(unsigned short h) {
  unsigned int u = ((unsigned int)h) << 16;
  return __builtin_bit_cast(float, u);
}
__device__ __forceinline__ f32x4 mfma16(int4 a, int4 b, f32x4 c) {
  return __builtin_amdgcn_mfma_f32_16x16x32_bf16(
      __builtin_bit_cast(bf16x8, a), __builtin_bit_cast(bf16x8, b), c, 0, 0, 0);
}
__device__ __forceinline__ float sig_(float x) { return 1.0f / (1.0f + __expf(-x)); }
__device__ __forceinline__ float tanh_(float x) {
  float ax = fabsf(x);
  float e  = __expf(2.0f * ax);
  float t  = 1.0f - 2.0f / (e + 1.0f);
  return x < 0.0f ? -t : t;
}

// ---- coherence-point (cross-XCD) access helpers ----
__device__ __forceinline__ void issue_ld16(const unsigned short* p, int4& d) {
  asm volatile("global_load_dwordx4 %0, %1, off sc0 sc1"
               : "=v"(d) : "v"(p) : "memory");
}
__device__ __forceinline__ void st_wt128(unsigned short* p, int4 v) {
  unsigned long long lo = ((unsigned long long)(unsigned int)v.y << 32) | (unsigned int)v.x;
  unsigned long long hi = ((unsigned long long)(unsigned int)v.w << 32) | (unsigned int)v.z;
  __hip_atomic_store((unsigned long long*)p,     lo, __ATOMIC_RELAXED, __HIP_MEMORY_SCOPE_AGENT);
  __hip_atomic_store((unsigned long long*)p + 1, hi, __ATOMIC_RELAXED, __HIP_MEMORY_SCOPE_AGENT);
}
__device__ __forceinline__ void wait_vm0() {
  asm volatile("s_waitcnt vmcnt(0)" ::: "memory");
}
__device__ __forceinline__ void st_wt16(unsigned short* p, unsigned short v) {
  __hip_atomic_store(p, v, __ATOMIC_RELAXED, __HIP_MEMORY_SCOPE_AGENT);
}
__device__ __forceinline__ void st_flag(int* p, int v) {
  __hip_atomic_store(p, v, __ATOMIC_RELAXED, __HIP_MEMORY_SCOPE_AGENT);
}
__device__ __forceinline__ void poll16(const int* f, int need) {
  int lane = threadIdx.x & 63;
  int v = need;
  if (lane < 16) v = __hip_atomic_load((int*)(f + lane), __ATOMIC_RELAXED, __HIP_MEMORY_SCOPE_AGENT);
  while (__any(v < need)) {
    __builtin_amdgcn_s_sleep(1);
    if (lane < 16) v = __hip_atomic_load((int*)(f + lane), __ATOMIC_RELAXED, __HIP_MEMORY_SCOPE_AGENT);
  }
}

// ---------------------------------------------------------------------------
__global__ void cvt_bf16(const float* __restrict__ src, unsigned short* __restrict__ dst, int n4) {
  int i = blockIdx.x * blockDim.x + threadIdx.x;
  if (i < n4) {
    float4 v = *(const float4*)(src + (size_t)i * 4);
    ushort4 o;
    o.x = f2bf(v.x); o.y = f2bf(v.y); o.z = f2bf(v.z); o.w = f2bf(v.w);
    *(ushort4*)(dst + (size_t)i * 4) = o;
  }
}

// X (64,1024,128) f32 -> Xt row (t*64+b), 128 bf16
__global__ void xt_k(const float* __restrict__ X, unsigned short* __restrict__ Xt) {
  int idx = blockIdx.x * 256 + threadIdx.x;
  int i4 = idx & 31, rest = idx >> 5;
  int t = rest & 1023, b = rest >> 10;
  float4 v = *(const float4*)(X + (size_t)(b * 1024 + t) * 128 + i4 * 4);
  ushort4 o;
  o.x = f2bf(v.x); o.y = f2bf(v.y); o.z = f2bf(v.z); o.w = f2bf(v.w);
  *(ushort4*)(Xt + (size_t)(t * 64 + b) * 128 + i4 * 4) = o;
}

// ---------------------------------------------------------------------------
// C[M,N] = A[M,K] @ W[N,K]^T  (bf16). mode 0: bf16 out; mode 2: fp32+bias,
// row remap m=(t*64+b) -> out row b*1024+t (final Y).
// ---------------------------------------------------------------------------
__global__ __launch_bounds__(256)
void gemm_bt(const unsigned short* __restrict__ A, const unsigned short* __restrict__ W,
             void* __restrict__ Cout, const float* __restrict__ bias,
             int M, int N, int K, int mode) {
  __shared__ unsigned short As[128][72];
  __shared__ unsigned short Bs[128][72];
  const int tid  = threadIdx.x;
  const int lane = tid & 63;
  const int wave = tid >> 6;
  const int wr = wave >> 1, wc = wave & 1;
  const int m0 = blockIdx.x * 128, n0 = blockIdx.y * 128;

  f32x4 acc[4][4];
  for (int i = 0; i < 4; i++)
    for (int j = 0; j < 4; j++) acc[i][j] = f32x4{0.f, 0.f, 0.f, 0.f};

  for (int k0 = 0; k0 < K; k0 += 64) {
    int4 va[4], vb[4];
#pragma unroll
    for (int it = 0; it < 4; it++) {
      int q = tid + it * 256;
      int r = q >> 3, kc = q & 7;
      va[it] = *(const int4*)(A + (size_t)(m0 + r) * K + k0 + kc * 8);
      vb[it] = *(const int4*)(W + (size_t)(n0 + r) * K + k0 + kc * 8);
    }
    __syncthreads();
#pragma unroll
    for (int it = 0; it < 4; it++) {
      int q = tid + it * 256;
      int r = q >> 3, kc = q & 7;
      *(int4*)&As[r][kc * 8] = va[it];
      *(int4*)&Bs[r][kc * 8] = vb[it];
    }
    __syncthreads();
#pragma unroll
    for (int kc = 0; kc < 2; kc++) {
      int koff = kc * 32 + (lane >> 4) * 8;
      int4 af[4], bfr[4];
#pragma unroll
      for (int mt = 0; mt < 4; mt++) af[mt]  = *(const int4*)&As[wr * 64 + mt * 16 + (lane & 15)][koff];
#pragma unroll
      for (int nt = 0; nt < 4; nt++) bfr[nt] = *(const int4*)&Bs[wc * 64 + nt * 16 + (lane & 15)][koff];
#pragma unroll
      for (int mt = 0; mt < 4; mt++)
#pragma unroll
        for (int nt = 0; nt < 4; nt++)
          acc[mt][nt] = mfma16(af[mt], bfr[nt], acc[mt][nt]);
    }
  }

#pragma unroll
  for (int mt = 0; mt < 4; mt++)
#pragma unroll
    for (int nt = 0; nt < 4; nt++)
#pragma unroll
      for (int rg = 0; rg < 4; rg++) {
        int m = m0 + wr * 64 + mt * 16 + (lane >> 4) * 4 + rg;
        int n = n0 + wc * 64 + nt * 16 + (lane & 15);
        float v = acc[mt][nt][rg];
        if (mode == 0) {
          ((unsigned short*)Cout)[(size_t)m * N + n] = f2bf(v);
        } else {
          ((float*)Cout)[(size_t)((m & 63) * 1024 + (m >> 6)) * N + n] = v + bias[n];
        }
      }
}

// ---------------------------------------------------------------------------
// Recurrence over one 256-step chunk. 64 WGs = 4 batch-groups x 16 col-slices
// (32 cols each). 2 waves: wave0 = r,z + u publish; wave1 = g + h publish.
// ---------------------------------------------------------------------------
__global__ __launch_bounds__(128)
void gru_rec(const float* __restrict__ Whz, const float* __restrict__ Whr,
             const float* __restrict__ Whg,
             const float* __restrict__ bz, const float* __restrict__ br,
             const float* __restrict__ bg,
             const unsigned short* __restrict__ Pz, const unsigned short* __restrict__ Pr,
             const unsigned short* __restrict__ Pg,   // chunk-local (CT,B,H) bf16
             const float* __restrict__ h0,            // (B,L,H) fp32 original
             float* __restrict__ hstate,              // (B,H) fp32 carry
             unsigned short* __restrict__ Hbuf,       // (S,B,H) bf16 full
             unsigned short* __restrict__ hbc,        // 2 slots x (B,H) bf16
             unsigned short* __restrict__ ubc,        // (B,H) bf16
             int* __restrict__ hflag, int* __restrict__ uflag,  // (4,16)
             float* __restrict__ hidout,              // (B,L,H) fp32
             int layer, int tokbase, int tstart) {
  const int bid  = blockIdx.x;
  const int g    = bid & 3;          // batch group (16 rows)
  const int mem  = bid >> 2;         // col slice 0..15
  const int cbase = mem * CC;
  const int tid  = threadIdx.x;
  const int lane = tid & 63;
  const int wave = tid >> 6;         // 0..1

  // K-major weight LDS: [gate 0=z,1=r,2=g][K-octet 0..63][col 0..31][8 bf16]
  __shared__ unsigned short Whs[3][64][32][8];   // 98,304 B
  __shared__ float hloc[16][CC + 1];
  __shared__ float zbuf[16][CC + 1];
  __shared__ unsigned short un[16][40];
  __shared__ unsigned short hnew[16][40];

  // ---- stage Wh fp32 -> bf16 K-major LDS ----
  {
    const float* wsrc[3] = { Whz + (size_t)layer * 262144,
                             Whr + (size_t)layer * 262144,
                             Whg + (size_t)layer * 262144 };
    for (int idx = tid; idx < 12288; idx += 128) {
      int gate = idx >> 12;            // 0..2
      int r = idx & 4095;
      int c = r >> 7, k4 = r & 127;
      float4 v = *(const float4*)(wsrc[gate] + (size_t)(cbase + c) * 512 + k4 * 4);
      int o = k4 >> 1, base = (k4 & 1) * 4;
      Whs[gate][o][c][base + 0] = f2bf(v.x);
      Whs[gate][o][c][base + 1] = f2bf(v.y);
      Whs[gate][o][c][base + 2] = f2bf(v.z);
      Whs[gate][o][c][base + 3] = f2bf(v.w);
    }
  }
  // ---- init h state + publish into hbc slot 0 ----
  for (int q = tid; q < 16 * CC; q += 128) {
    int row = q >> 5, c = q & 31;
    int b = g * 16 + row;
    float v = (tstart == 0)
                ? h0[(size_t)b * 1536 + layer * 512 + cbase + c]
                : hstate[(size_t)b * 512 + cbase + c];
    hloc[row][c] = v;
    st_wt16(&hbc[b * 512 + cbase + c], f2bf(v));   // slot 0
  }
  wait_vm0();
  __syncthreads();
  if (tid == 0) st_flag(&hflag[g * 16 + mem], tokbase + 1);

  const int* hfg = hflag + g * 16;
  const int* ufg = uflag + g * 16;
  const int myflag = g * 16 + mem;
  const int l15 = lane & 15;
  const int kq  = lane >> 4;

  float bzc[2], brc[2], bgc[2];
#pragma unroll
  for (int T = 0; T < 2; T++) {
    bzc[T] = bz[(size_t)layer * 512 + cbase + T * 16 + l15];
    brc[T] = br[(size_t)layer * 512 + cbase + T * 16 + l15];
    bgc[T] = bg[(size_t)layer * 512 + cbase + T * 16 + l15];
  }

  for (int tl = 0; tl < CT; tl++) {
    const int slot_r = tl & 1;
    const int slot_w = (tl + 1) & 1;

    if (wave == 0) {
      // ---- prefetch P (cached, independent of h) ----
      float pr[2][4], pz[2][4];
#pragma unroll
      for (int T = 0; T < 2; T++)
#pragma unroll
        for (int rg = 0; rg < 4; rg++) {
          size_t off = (size_t)tl * 32768 + (size_t)(g * 16 + kq * 4 + rg) * 512 + cbase + T * 16 + l15;
          pr[T][rg] = bf2f(Pr[off]);
          pz[T][rg] = bf2f(Pz[off]);
        }
      // ---- hop 1: wait h(t-1), load ----
      poll16(hfg, tokbase + 1 + tl);
      int4 hf[16];
      const unsigned short* hr = hbc + (size_t)slot_r * 32768 + (g * 16 + l15) * 512 + kq * 8;
#pragma unroll
      for (int kc = 0; kc < 16; kc++) issue_ld16(hr + kc * 32, hf[kc]);
      wait_vm0();
      // ---- r gate first (feeds the u-hop) ----
      f32x4 ar[2] = { f32x4{0.f,0.f,0.f,0.f}, f32x4{0.f,0.f,0.f,0.f} };
#pragma unroll
      for (int kc = 0; kc < 16; kc++)
#pragma unroll
        for (int T = 0; T < 2; T++)
          ar[T] = mfma16(hf[kc], *(const int4*)&Whs[1][kc * 4 + kq][T * 16 + l15][0], ar[T]);
#pragma unroll
      for (int T = 0; T < 2; T++)
#pragma unroll
        for (int rg = 0; rg < 4; rg++) {
          int row = kq * 4 + rg, c = T * 16 + l15;
          float rv = sig_(ar[T][rg] + pr[T][rg] + brc[T]);
          un[row][c] = f2bf(rv * hloc[row][c]);
        }
      // coalesced u publish (this wave alone: 64 lanes x 16B = 1 KB slice)
      {
        int4 v = *(const int4*)&un[lane >> 2][(lane & 3) * 8];
        st_wt128(ubc + (g * 16 + (lane >> 2)) * 512 + cbase + (lane & 3) * 8, v);
      }
      // ---- z gate (overlaps u store-ack) ----
      f32x4 az[2] = { f32x4{0.f,0.f,0.f,0.f}, f32x4{0.f,0.f,0.f,0.f} };
#pragma unroll
      for (int kc = 0; kc < 16; kc++)
#pragma unroll
        for (int T = 0; T < 2; T++)
          az[T] = mfma16(hf[kc], *(const int4*)&Whs[0][kc * 4 + kq][T * 16 + l15][0], az[T]);
#pragma unroll
      for (int T = 0; T < 2; T++)
#pragma unroll
        for (int rg = 0; rg < 4; rg++)
          zbuf[kq * 4 + rg][T * 16 + l15] = sig_(az[T][rg] + pz[T][rg] + bzc[T]);
      wait_vm0();
      if (lane == 0) st_flag((int*)&uflag[myflag], tokbase + 1 + tl);
    } else {
      // ---- prefetch Pg ----
      float pg[2][4];
#pragma unroll
      for (int T = 0; T < 2; T++)
#pragma unroll
        for (int rg = 0; rg < 4; rg++)
          pg[T][rg] = bf2f(Pg[(size_t)tl * 32768 + (size_t)(g * 16 + kq * 4 + rg) * 512 + cbase + T * 16 + l15]);
      // ---- hop 2: wait u(t), load ----
      poll16(ufg, tokbase + 1 + tl);
      int4 uf[16];
      const unsigned short* ur = ubc + (g * 16 + l15) * 512 + kq * 8;
#pragma unroll
      for (int kc = 0; kc < 16; kc++) issue_ld16(ur + kc * 32, uf[kc]);
      wait_vm0();
      f32x4 ag[2] = { f32x4{0.f,0.f,0.f,0.f}, f32x4{0.f,0.f,0.f,0.f} };
#pragma unroll
      for (int kc = 0; kc < 16; kc++)
#pragma unroll
        for (int T = 0; T < 2; T++)
          ag[T] = mfma16(uf[kc], *(const int4*)&Whs[2][kc * 4 + kq][T * 16 + l15][0], ag[T]);
      // stash pre-activation + pg in ag for post-barrier blend
#pragma unroll
      for (int T = 0; T < 2; T++)
#pragma unroll
        for (int rg = 0; rg < 4; rg++)
          ag[T][rg] += pg[T][rg] + bgc[T];
      __syncthreads();   // A: zbuf ready (wave0 wrote it pre-barrier)
#pragma unroll
      for (int T = 0; T < 2; T++)
#pragma unroll
        for (int rg = 0; rg < 4; rg++) {
          int row = kq * 4 + rg, c = T * 16 + l15;
          float gv = tanh_(ag[T][rg]);
          float z  = zbuf[row][c];
          float h  = hloc[row][c];
          float hn = z * h + (1.0f - z) * gv;
          hloc[row][c] = hn;
          hnew[row][c] = f2bf(hn);
        }
      // coalesced h publish + Hbuf
      {
        int4 v = *(const int4*)&hnew[lane >> 2][(lane & 3) * 8];
        st_wt128(hbc + (size_t)slot_w * 32768 + (g * 16 + (lane >> 2)) * 512 + cbase + (lane & 3) * 8, v);
        *(int4*)&Hbuf[(size_t)(tstart + tl) * 32768 + (g * 16 + (lane >> 2)) * 512 + cbase + (lane & 3) * 8] = v;
      }
      wait_vm0();
      if (lane == 0) st_flag((int*)&hflag[myflag], tokbase + 2 + tl);
    }
    if (wave == 0) __syncthreads();  // A (wave0 side)
    __syncthreads();                 // B: hloc/zbuf safe for next step
  }

  // ---- chunk carry-out ----
  for (int q = tid; q < 16 * CC; q += 128) {
    int row = q >> 5, c = q & 31;
    int b = g * 16 + row;
    float v = hloc[row][c];
    hstate[(size_t)b * 512 + cbase + c] = v;
    if (tstart + CT == 1024)
      hidout[(size_t)b * 1536 + layer * 512 + cbase + c] = v;
  }
}

// ---------------------------------------------------------------------------
// launcher
// ---------------------------------------------------------------------------
extern "C" void kernel_launch(void* const* d_in, const int* in_sizes, int n_in,
                              void* d_out, int out_size, void* d_ws, size_t ws_size,
                              hipStream_t stream) {
  const float* X    = (const float*)d_in[0];
  const float* H0   = (const float*)d_in[1];
  const float* Wx0z = (const float*)d_in[2];
  const float* Wx0r = (const float*)d_in[3];
  const float* Wx0g = (const float*)d_in[4];
  const float* Wxz  = (const float*)d_in[5];
  const float* Wxr  = (const float*)d_in[6];
  const float* Wxg  = (const float*)d_in[7];
  const float* Whz  = (const float*)d_in[8];
  const float* Whr  = (const float*)d_in[9];
  const float* Whg  = (const float*)d_in[10];
  const float* bz   = (const float*)d_in[11];
  const float* br   = (const float*)d_in[12];
  const float* bg   = (const float*)d_in[13];
  const float* Wy   = (const float*)d_in[14];
  const float* by   = (const float*)d_in[15];

  char* w = (char*)d_ws;
  unsigned short* Xt    = (unsigned short*)(w + 0);          // 16,777,216
  unsigned short* Wx0zb = (unsigned short*)(w + 16777216);   // 131,072
  unsigned short* Wx0rb = (unsigned short*)(w + 16908288);
  unsigned short* Wx0gb = (unsigned short*)(w + 17039360);
  unsigned short* Wxzb  = (unsigned short*)(w + 17170432);   // 1,048,576
  unsigned short* Wxrb  = (unsigned short*)(w + 18219008);
  unsigned short* Wxgb  = (unsigned short*)(w + 19267584);
  unsigned short* Wyb   = (unsigned short*)(w + 20316160);   // 131,072
  unsigned short* Pz    = (unsigned short*)(w + 20447232);   // 16,777,216 each
  unsigned short* Pr    = (unsigned short*)(w + 37224448);
  unsigned short* Pg    = (unsigned short*)(w + 54001664);
  unsigned short* Hb    = (unsigned short*)(w + 70778880);   // 67,108,864
  float*          hst   = (float*)(w + 137887744);           // 131,072
  unsigned short* hbc   = (unsigned short*)(w + 138018816);  // 131,072
  unsigned short* ubc   = (unsigned short*)(w + 138149888);  // 65,536
  int* hflag            = (int*)(w + 138215424);             // 256
  int* uflag            = (int*)(w + 138216448);             // 256
  // end ~138,217,000 bytes -- byte-range proven in rounds 2-3

  (void)hipMemsetAsync(hflag, 0, 2048, stream);

  auto cvt = [&](const float* s, unsigned short* d, int n) {
    int n4 = n / 4;
    cvt_bf16<<<dim3((n4 + 255) / 256), dim3(256), 0, stream>>>(s, d, n4);
  };
  xt_k<<<dim3(8192), dim3(256), 0, stream>>>(X, Xt);
  cvt(Wx0z, Wx0zb, 65536);
  cvt(Wx0r, Wx0rb, 65536);
  cvt(Wx0g, Wx0gb, 65536);
  cvt(Wxz, Wxzb, 524288);
  cvt(Wxr, Wxrb, 524288);
  cvt(Wxg, Wxgb, 524288);
  cvt(Wy, Wyb, 65536);

  float* hidout = (float*)d_out + 8388608;

  for (int layer = 0; layer < 3; layer++) {
    for (int chunk = 0; chunk < 4; chunk++) {
      int tstart = chunk * CT;
      const unsigned short *Ap, *wz, *wr_, *wg;
      int K;
      if (layer == 0) {
        Ap = Xt + (size_t)tstart * 64 * 128;
        wz = Wx0zb; wr_ = Wx0rb; wg = Wx0gb; K = 128;
      } else {
        Ap = Hb + (size_t)tstart * 64 * 512;
        wz = Wxzb + (size_t)(layer - 1) * 262144;
        wr_ = Wxrb + (size_t)(layer - 1) * 262144;
        wg = Wxgb + (size_t)(layer - 1) * 262144;
        K = 512;
      }
      gemm_bt<<<dim3(128, 4), 256, 0, stream>>>(Ap, wz,  Pz, (const float*)nullptr, 16384, 512, K, 0);
      gemm_bt<<<dim3(128, 4), 256, 0, stream>>>(Ap, wr_, Pr, (const float*)nullptr, 16384, 512, K, 0);
      gemm_bt<<<dim3(128, 4), 256, 0, stream>>>(Ap, wg,  Pg, (const float*)nullptr, 16384, 512, K, 0);

      int tokbase = (layer * 4 + chunk) * 512;
      gru_rec<<<dim3(64), dim3(128), 0, stream>>>(
          Whz, Whr, Whg, bz, br, bg, Pz, Pr, Pg, H0, hst, Hb, hbc, ubc,
          hflag, uflag, hidout, layer, tokbase, tstart);
    }
  }

  // Y = H2 @ Wy^T + by  -> (B,S,O) fp32
  gemm_bt<<<dim3(512, 1), 256, 0, stream>>>(Hb, Wyb, d_out, by, 65536, 128, 512, 2);
}